// Round 6
// baseline (208.076 us; speedup 1.0000x reference)
//
#include <hip/hip_runtime.h>

// HellingerDistance: out[n][m] = 0.5*(rowsum_a[n] + rowsum_b[m]) - sqrt(a[n])·sqrt(b[m])
// N = M = 8192, D = 1024, f32 in/out.
// Round 6: B never touches LDS. Prep packs sqrt(b) into a fragment-ready layout
// (16-col x 8-k tiles) so B-fragments load global->reg fully coalesced (1KB/wave).
// A stays on gload_lds + both-sides swizzle, LDS drops to 64KB, DS-pipe floor
// 79us -> 50us; MFMA pipe becomes binding. Counted vmcnt(12) per tile.

#define NM 8192
#define DD 1024
#define NT 16  // K-tiles of 64

typedef __attribute__((ext_vector_type(8))) short bf16x8;
typedef __attribute__((ext_vector_type(4))) float f32x4;

#define AS1 __attribute__((address_space(1)))
#define AS3 __attribute__((address_space(3)))

#define SCHED0 __builtin_amdgcn_sched_barrier(0)
#define WAIT_LGKM(n) do { SCHED0; asm volatile("s_waitcnt lgkmcnt(" #n ")" ::: "memory"); SCHED0; } while (0)
#define WAIT_VM(n)   do { SCHED0; asm volatile("s_waitcnt vmcnt(" #n ")" ::: "memory"); SCHED0; } while (0)

// f32 -> bf16 round-to-nearest-even (inputs positive, no NaN/Inf)
static __device__ __forceinline__ unsigned short f2bf(float f) {
  unsigned int u = __float_as_uint(f);
  u += 0x7FFFu + ((u >> 16) & 1u);
  return (unsigned short)(u >> 16);
}

// ---------------- kernel 1a: sqrt(a) -> bf16 row-major + rowsums -----------
__global__ __launch_bounds__(256)
void hell_prepA(const float* __restrict__ A, unsigned short* __restrict__ SA,
                float* __restrict__ RA) {
  __shared__ float wsum[4];
  const int row = blockIdx.x;
  const float* src = A + (size_t)row * DD;
  unsigned short* dst = SA + (size_t)row * DD;
  const int t = threadIdx.x;
  const float4 v = ((const float4*)src)[t];
  ushort4 p;
  p.x = f2bf(sqrtf(v.x)); p.y = f2bf(sqrtf(v.y));
  p.z = f2bf(sqrtf(v.z)); p.w = f2bf(sqrtf(v.w));
  ((ushort4*)dst)[t] = p;
  float s = (v.x + v.y) + (v.z + v.w);
#pragma unroll
  for (int m = 1; m < 64; m <<= 1) s += __shfl_xor(s, m, 64);
  if ((t & 63) == 0) wsum[t >> 6] = s;
  __syncthreads();
  if (t == 0) RA[row] = wsum[0] + wsum[1] + wsum[2] + wsum[3];
}

// ---------------- kernel 1b: sqrt(b) -> fragment-packed bf16 + rowsums -----
// Packed layout (16B units): unit(c16, kb, lo) = c16*2048 + kb*16 + lo
// holds sqrt(b)[c16*16+lo][kb*8 .. kb*8+7]. A wave's B-fragment (16 cols x
// 8 k x 4 k-groups) is then 64 consecutive units = 1024B contiguous.
__global__ __launch_bounds__(256)
void hell_prepB(const float* __restrict__ B, unsigned short* __restrict__ SBp,
                float* __restrict__ RB) {
  __shared__ float part[256];
  const int c16 = blockIdx.x;       // 0..511
  const int t = threadIdx.x;
  const int lor = t >> 4;           // row-within-16 handled by this thread
  const float* src = B + (size_t)(c16 * 16 + lor) * DD;
  float sum = 0.f;
#pragma unroll
  for (int i = 0; i < 8; ++i) {
    const int kb = (t & 15) + 16 * i;      // 0..127, coalesced reads
    const float4 v0 = ((const float4*)(src + kb * 8))[0];
    const float4 v1 = ((const float4*)(src + kb * 8))[1];
    sum += ((v0.x + v0.y) + (v0.z + v0.w)) + ((v1.x + v1.y) + (v1.z + v1.w));
    bf16x8 p;
    p[0] = (short)f2bf(sqrtf(v0.x)); p[1] = (short)f2bf(sqrtf(v0.y));
    p[2] = (short)f2bf(sqrtf(v0.z)); p[3] = (short)f2bf(sqrtf(v0.w));
    p[4] = (short)f2bf(sqrtf(v1.x)); p[5] = (short)f2bf(sqrtf(v1.y));
    p[6] = (short)f2bf(sqrtf(v1.z)); p[7] = (short)f2bf(sqrtf(v1.w));
    const int u = kb * 16 + lor;
    *(bf16x8*)(SBp + ((size_t)c16 * 2048 + u) * 8) = p;
  }
  part[t] = sum;
  __syncthreads();
  if (t < 16) {
    float s = 0.f;
#pragma unroll
    for (int j = 0; j < 16; ++j) s += part[t * 16 + j];
    RB[c16 * 16 + t] = s;
  }
}

// ---------------- kernel 2: 256^2 GEMM, A via LDS, B direct-to-reg ---------
__global__ __launch_bounds__(512, 2)
void hell_gemm5(const unsigned short* __restrict__ SA,
                const unsigned short* __restrict__ SBp,
                const float* __restrict__ RA, const float* __restrict__ RB,
                float* __restrict__ C) {
  __shared__ __attribute__((aligned(16))) char lds[65536]; // 2 x 32KB A-buffers

  const int t = threadIdx.x;
  const int lane = t & 63;
  const int wave = t >> 6;
  const int wm = wave >> 2;   // 0..1 -> rows wm*128
  const int wn = wave & 3;    // 0..3 -> cols wn*64

  // bijective XCD swizzle: nwg = 1024, 8 XCDs, chunk = 128
  const int wg = blockIdx.x;
  const int s = (wg & 7) * 128 + (wg >> 3);
  const int brow = (s >> 5) * 256;
  const int bcol = (s & 31) * 256;

  // A staging: thread t covers LDS row (t>>3) of each 64-row group, chunk t&7;
  // global source chunk pre-swizzled (both-sides XOR, rule 21).
  const int sw = ((t >> 3) & 7) ^ (t & 7);
  const unsigned short* ga = SA + (size_t)(brow + (t >> 3)) * DD + sw * 8;

  const int hi = lane >> 4;   // 0..3
  const int lo = lane & 15;
  const int x7 = lo & 7;      // fragment-row & 7 for swizzled reads

  // B base: fragment-packed, wave reads 1KB contiguous per fragment
  const char* Bbase = (const char*)SBp +
      ((size_t)((bcol >> 4) + wn * 4) * 32768 + hi * 256 + lo * 16);

  f32x4 acc[8][4];
#pragma unroll
  for (int m = 0; m < 8; ++m)
#pragma unroll
    for (int n = 0; n < 4; ++n) acc[m][n] = (f32x4){0.f, 0.f, 0.f, 0.f};

  bf16x8 A0[2][2], A1[2][2];  // A-quadrant ping-pong
  bf16x8 bfr[4][2];           // B single set (reloaded per tile)

#define STAGE_A(KT2, P)                                                         \
  do {                                                                          \
    const size_t ko_ = (size_t)(KT2) * 64;                                      \
    _Pragma("unroll")                                                           \
    for (int i_ = 0; i_ < 4; ++i_)                                              \
      __builtin_amdgcn_global_load_lds(                                         \
          (const AS1 unsigned int*)(ga + (size_t)(i_ * 64) * DD + ko_),         \
          (AS3 unsigned int*)(lds + (P)*32768 + i_ * 8192 + t * 16), 16, 0, 0); \
  } while (0)

#define LOADB(KT)                                                               \
  do {                                                                          \
    _Pragma("unroll")                                                           \
    for (int n_ = 0; n_ < 4; ++n_)                                              \
      _Pragma("unroll")                                                         \
      for (int k_ = 0; k_ < 2; ++k_)                                            \
        bfr[n_][k_] = *(const bf16x8*)(Bbase + n_ * 32768 + (KT)*2048 + k_ * 1024); \
  } while (0)

#define LDA(ASet, Ab, q)                                                        \
  do {                                                                          \
    _Pragma("unroll")                                                           \
    for (int m_ = 0; m_ < 2; ++m_) {                                            \
      const char* ra_ = (Ab) + (wm * 128 + ((q)*2 + m_) * 16 + lo) * 128;       \
      _Pragma("unroll")                                                         \
      for (int k_ = 0; k_ < 2; ++k_)                                            \
        ASet[m_][k_] = *(const bf16x8*)(ra_ + (((k_ * 4 + hi) ^ x7) << 4));     \
    }                                                                           \
  } while (0)

#define MFMA_Q(q, ASet)                                                         \
  do {                                                                          \
    __builtin_amdgcn_s_setprio(1);                                              \
    _Pragma("unroll")                                                           \
    for (int m_ = 0; m_ < 2; ++m_)                                              \
      _Pragma("unroll")                                                         \
      for (int n_ = 0; n_ < 4; ++n_)                                            \
        _Pragma("unroll")                                                       \
        for (int k_ = 0; k_ < 2; ++k_)                                          \
          acc[(q)*2 + m_][n_] = __builtin_amdgcn_mfma_f32_16x16x32_bf16(        \
              ASet[m_][k_], bfr[n_][k_], acc[(q)*2 + m_][n_], 0, 0, 0);         \
    __builtin_amdgcn_s_setprio(0);                                              \
  } while (0)

  // prologue: B(0) first (oldest in FIFO), then A(0), A(1)
  LOADB(0);
  STAGE_A(0, 0);
  STAGE_A(1, 1);
  WAIT_VM(4);                     // B(0)+A(0) landed; A(1)'s 4 still flying
  __builtin_amdgcn_s_barrier();

#pragma unroll 1
  for (int kt = 0; kt < NT; ++kt) {
    const int p = kt & 1;
    const char* Ab = lds + p * 32768;

    // 4-phase A-read / MFMA interleave (counted lgkm; B already in regs)
    LDA(A0, Ab, 0); SCHED0;
    LDA(A1, Ab, 1); WAIT_LGKM(4); MFMA_Q(0, A0); SCHED0;
    LDA(A0, Ab, 2); WAIT_LGKM(4); MFMA_Q(1, A1); SCHED0;
    LDA(A1, Ab, 3); WAIT_LGKM(4); MFMA_Q(2, A0); SCHED0;
    WAIT_LGKM(0);
    __builtin_amdgcn_s_barrier();   // all waves done reading buf[p]

    MFMA_Q(3, A1);                  // last quadrant: regs only
    SCHED0;
    if (kt + 1 < NT) LOADB(kt + 1); // overwrite B set (WAR-safe: q3 done)
    SCHED0;
    if (kt + 2 < NT) {
      STAGE_A(kt + 2, p);           // buf[p] free since mid-tile barrier
      WAIT_VM(12);                  // A(kt+1)+B(kt+1) landed; 12 in flight
      __builtin_amdgcn_s_barrier();
    } else if (kt + 1 < NT) {
      WAIT_VM(8);                   // A(15) landed; B(15)'s 8 in flight
      __builtin_amdgcn_s_barrier();
    }
  }

#undef MFMA_Q
#undef LDA
#undef LOADB
#undef STAGE_A

  // epilogue: C/D layout col=lane&15, row=(lane>>4)*4+j
  float hrb[4];
#pragma unroll
  for (int n = 0; n < 4; ++n)
    hrb[n] = 0.5f * RB[bcol + wn * 64 + n * 16 + lo];
#pragma unroll
  for (int m = 0; m < 8; ++m) {
    const int rbase = wm * 128 + m * 16 + hi * 4;
#pragma unroll
    for (int j = 0; j < 4; ++j) {
      const int row = rbase + j;
      const float ha = 0.5f * RA[brow + row];
      float* orow = C + (size_t)(brow + row) * NM + bcol;
#pragma unroll
      for (int n = 0; n < 4; ++n)
        orow[wn * 64 + n * 16 + lo] = ha + hrb[n] - acc[m][n][j];
    }
  }
}

// ---------------- fallback: fused kernel (if ws too small) -----------------
static __device__ __forceinline__ int swz(int row, int colbytes) {
  return (row * 128 + colbytes) ^ ((row & 7) << 4);
}

__global__ __launch_bounds__(256, 2)
void hellinger_fused(const float* __restrict__ A, const float* __restrict__ B,
                     float* __restrict__ C) {
  __shared__ unsigned short As[128 * 64];
  __shared__ unsigned short Bs[128 * 64];
  __shared__ float sA[128];
  __shared__ float sB[128];

  const int t = threadIdx.x;
  const int lane = t & 63;
  const int wave = t >> 6;
  const int wrow = (wave >> 1) * 64;
  const int wcol = (wave & 1) * 64;
  const int brow = blockIdx.y * 128;
  const int bcol = blockIdx.x * 128;
  const int sr = t >> 4;
  const int sc = (t & 15) * 4;

  const float* ap = A + (size_t)(brow + sr) * DD + sc;
  const float* bp = B + (size_t)(bcol + sr) * DD + sc;

  float racc[8], cacc[8];
#pragma unroll
  for (int i = 0; i < 8; ++i) { racc[i] = 0.f; cacc[i] = 0.f; }

  f32x4 acc[4][4];
#pragma unroll
  for (int m = 0; m < 4; ++m)
#pragma unroll
    for (int n = 0; n < 4; ++n) acc[m][n] = (f32x4){0.f, 0.f, 0.f, 0.f};

  for (int kt = 0; kt < DD / 64; ++kt) {
#pragma unroll
    for (int i = 0; i < 8; ++i) {
      const float4 v = *(const float4*)(ap + (size_t)(i * 16) * DD + kt * 64);
      racc[i] += (v.x + v.y) + (v.z + v.w);
      ushort4 p;
      p.x = f2bf(sqrtf(v.x)); p.y = f2bf(sqrtf(v.y));
      p.z = f2bf(sqrtf(v.z)); p.w = f2bf(sqrtf(v.w));
      *(ushort4*)((char*)As + swz(i * 16 + sr, sc * 2)) = p;
    }
#pragma unroll
    for (int i = 0; i < 8; ++i) {
      const float4 v = *(const float4*)(bp + (size_t)(i * 16) * DD + kt * 64);
      cacc[i] += (v.x + v.y) + (v.z + v.w);
      ushort4 p;
      p.x = f2bf(sqrtf(v.x)); p.y = f2bf(sqrtf(v.y));
      p.z = f2bf(sqrtf(v.z)); p.w = f2bf(sqrtf(v.w));
      *(ushort4*)((char*)Bs + swz(i * 16 + sr, sc * 2)) = p;
    }
    __syncthreads();
#pragma unroll
    for (int kk = 0; kk < 2; ++kk) {
      const int koffb = kk * 64 + (lane >> 4) * 16;
      bf16x8 af[4], bfr[4];
#pragma unroll
      for (int m = 0; m < 4; ++m)
        af[m] = *(const bf16x8*)((const char*)As + swz(wrow + m * 16 + (lane & 15), koffb));
#pragma unroll
      for (int n = 0; n < 4; ++n)
        bfr[n] = *(const bf16x8*)((const char*)Bs + swz(wcol + n * 16 + (lane & 15), koffb));
#pragma unroll
      for (int m = 0; m < 4; ++m)
#pragma unroll
        for (int n = 0; n < 4; ++n)
          acc[m][n] = __builtin_amdgcn_mfma_f32_16x16x32_bf16(af[m], bfr[n], acc[m][n], 0, 0, 0);
    }
    __syncthreads();
  }

#pragma unroll
  for (int i = 0; i < 8; ++i) {
#pragma unroll
    for (int mask = 1; mask < 16; mask <<= 1) {
      racc[i] += __shfl_xor(racc[i], mask, 64);
      cacc[i] += __shfl_xor(cacc[i], mask, 64);
    }
  }
  if ((t & 15) == 0) {
#pragma unroll
    for (int i = 0; i < 8; ++i) { sA[i * 16 + sr] = racc[i]; sB[i * 16 + sr] = cacc[i]; }
  }
  __syncthreads();

#pragma unroll
  for (int m = 0; m < 4; ++m) {
    const int rbase = wrow + m * 16 + (lane >> 4) * 4;
#pragma unroll
    for (int j = 0; j < 4; ++j) {
      const int row = rbase + j;
      const float ha = 0.5f * sA[row];
      float* orow = C + (size_t)(brow + row) * NM + bcol;
#pragma unroll
      for (int n = 0; n < 4; ++n) {
        const int col = wcol + n * 16 + (lane & 15);
        orow[col] = ha + 0.5f * sB[col] - acc[m][n][j];
      }
    }
  }
}

extern "C" void kernel_launch(void* const* d_in, const int* in_sizes, int n_in,
                              void* d_out, int out_size, void* d_ws, size_t ws_size,
                              hipStream_t stream) {
  const float* a = (const float*)d_in[0];
  const float* b = (const float*)d_in[1];
  float* out = (float*)d_out;

  const size_t mat_bytes = (size_t)NM * DD * sizeof(unsigned short); // 16 MB
  const size_t need = 2 * mat_bytes + 2 * (size_t)NM * sizeof(float);

  if (ws_size >= need) {
    unsigned short* SA  = (unsigned short*)d_ws;
    unsigned short* SBp = (unsigned short*)((char*)d_ws + mat_bytes);
    float* RA = (float*)((char*)d_ws + 2 * mat_bytes);
    float* RB = RA + NM;
    hipLaunchKernelGGL(hell_prepA, dim3(NM), dim3(256), 0, stream, a, SA, RA);
    hipLaunchKernelGGL(hell_prepB, dim3(NM / 16), dim3(256), 0, stream, b, SBp, RB);
    hipLaunchKernelGGL(hell_gemm5, dim3(32 * 32), dim3(512), 0, stream,
                       SA, SBp, RA, RB, out);
  } else {
    dim3 grid(NM / 128, NM / 128);
    hipLaunchKernelGGL(hellinger_fused, grid, dim3(256), 0, stream, a, b, out);
  }
}

// Round 7
// 169.268 us; speedup vs baseline: 1.2293x; 1.2293x over previous
//
#include <hip/hip_runtime.h>

// HellingerDistance: out[n][m] = 0.5*(rowsum_a[n] + rowsum_b[m]) - sqrt(a[n])·sqrt(b[m])
// N = M = 8192, D = 1024, f32 in/out.
// Round 7: faithful m201-style 8-phase schedule. 256x256/BK=64/8 waves.
// Per phase: {ds_reads, stage 1 half-tile (2 gload_lds), barrier, lgkm0,
// setprio+16 MFMA, barrier}. Staging ring 4-6 phases ahead of consumption;
// counted vmcnt(4) only at phases 4 and 8. Both-sides LDS XOR swizzle.

#define NM 8192
#define DD 1024

typedef __attribute__((ext_vector_type(8))) short bf16x8;
typedef __attribute__((ext_vector_type(4))) float f32x4;

#define AS1 __attribute__((address_space(1)))
#define AS3 __attribute__((address_space(3)))

#define SCHED0 __builtin_amdgcn_sched_barrier(0)
#define WAIT_LGKM0  do { SCHED0; asm volatile("s_waitcnt lgkmcnt(0)" ::: "memory"); SCHED0; } while (0)
#define WAIT_VM(n)  do { SCHED0; asm volatile("s_waitcnt vmcnt(" #n ")" ::: "memory"); SCHED0; } while (0)
#define BAR __builtin_amdgcn_s_barrier()

// f32 -> bf16 round-to-nearest-even (inputs positive, no NaN/Inf)
static __device__ __forceinline__ unsigned short f2bf(float f) {
  unsigned int u = __float_as_uint(f);
  u += 0x7FFFu + ((u >> 16) & 1u);
  return (unsigned short)(u >> 16);
}

// ---------------- kernel 1: sqrt -> bf16, exact f32 rowsums ----------------
__global__ __launch_bounds__(256)
void hell_prep(const float* __restrict__ A, const float* __restrict__ B,
               unsigned short* __restrict__ SA, unsigned short* __restrict__ SB,
               float* __restrict__ RA, float* __restrict__ RB) {
  __shared__ float wsum[4];
  const int row = blockIdx.x & (NM - 1);
  const bool isB = blockIdx.x >= NM;
  const float* src = (isB ? B : A) + (size_t)row * DD;
  unsigned short* dst = (isB ? SB : SA) + (size_t)row * DD;
  const int t = threadIdx.x;
  const float4 v = ((const float4*)src)[t];
  ushort4 p;
  p.x = f2bf(sqrtf(v.x)); p.y = f2bf(sqrtf(v.y));
  p.z = f2bf(sqrtf(v.z)); p.w = f2bf(sqrtf(v.w));
  ((ushort4*)dst)[t] = p;
  float s = (v.x + v.y) + (v.z + v.w);
#pragma unroll
  for (int m = 1; m < 64; m <<= 1) s += __shfl_xor(s, m, 64);
  if ((t & 63) == 0) wsum[t >> 6] = s;
  __syncthreads();
  if (t == 0) (isB ? RB : RA)[row] = wsum[0] + wsum[1] + wsum[2] + wsum[3];
}

// ---------------- kernel 2: 256^2 8-phase bf16 GEMM ------------------------
// LDS: buf d (d=0 even tiles, d=1 odd tiles) at d*65536.
// Within buf: A-tile rows 0..255 (128 B/row) at +0 (A-half h at +h*16384),
// B-tile at +32768. 16B chunk c of row r stored at c ^ (r&7) (both-sides swz).
__global__ __launch_bounds__(512, 2)
void hell_gemm6(const unsigned short* __restrict__ SA,
                const unsigned short* __restrict__ SB,
                const float* __restrict__ RA, const float* __restrict__ RB,
                float* __restrict__ C) {
  __shared__ __attribute__((aligned(16))) char lds[131072];

  const int t = threadIdx.x;
  const int lane = t & 63;
  const int wave = t >> 6;
  const int wm = wave >> 2;   // 0..1 -> rows wm*128
  const int wn = wave & 3;    // 0..3 -> cols wn*64

  // bijective XCD swizzle: nwg = 1024, 8 XCDs, chunk = 128
  const int wg = blockIdx.x;
  const int s = (wg & 7) * 128 + (wg >> 3);
  const int brow = (s >> 5) * 256;
  const int bcol = (s & 31) * 256;

  // staging: thread t covers LDS row (t>>3) of a 64-row group, chunk t&7;
  // global source chunk pre-swizzled (rule 21).
  const int sw = ((t >> 3) & 7) ^ (t & 7);

  const int hi = lane >> 4;   // 0..3
  const int lo = lane & 15;
  const int x7 = lo & 7;

  f32x4 acc[8][4];
#pragma unroll
  for (int m = 0; m < 8; ++m)
#pragma unroll
    for (int n = 0; n < 4; ++n) acc[m][n] = (f32x4){0.f, 0.f, 0.f, 0.f};

  bf16x8 af[2][2];   // per-phase A quadrant
  bf16x8 bfr[4][2];  // per-K-tile B fragments

  // stage one half-tile (128 rows x 64 k) = 2 gload_lds per thread
#define STAGE_HALF(MAT, BROW0, KT, LDSOFF)                                      \
  do {                                                                          \
    const unsigned short* g_ =                                                  \
        (MAT) + (size_t)((BROW0) + (t >> 3)) * DD + (size_t)(KT) * 64 + sw * 8; \
    __builtin_amdgcn_global_load_lds((const AS1 unsigned int*)g_,               \
        (AS3 unsigned int*)(lds + (LDSOFF) + t * 16), 16, 0, 0);                \
    __builtin_amdgcn_global_load_lds((const AS1 unsigned int*)(g_ + 64 * DD),   \
        (AS3 unsigned int*)(lds + (LDSOFF) + 8192 + t * 16), 16, 0, 0);         \
  } while (0)

#define SA_HALF(KT, BUF, H) STAGE_HALF(SA, brow + (H)*128, KT, (BUF)*65536 + (H)*16384)
#define SB_HALF(KT, BUF, H) STAGE_HALF(SB, bcol + (H)*128, KT, (BUF)*65536 + 32768 + (H)*16384)

#define LDA(BASE, q)                                                            \
  do {                                                                          \
    _Pragma("unroll")                                                           \
    for (int m_ = 0; m_ < 2; ++m_) {                                            \
      const char* ra_ = (BASE) + (wm * 128 + ((q)*2 + m_) * 16 + lo) * 128;     \
      _Pragma("unroll")                                                         \
      for (int k_ = 0; k_ < 2; ++k_)                                            \
        af[m_][k_] = *(const bf16x8*)(ra_ + (((k_ * 4 + hi) ^ x7) << 4));       \
    }                                                                           \
  } while (0)

#define LDB(BASE)                                                               \
  do {                                                                          \
    _Pragma("unroll")                                                           \
    for (int n_ = 0; n_ < 4; ++n_) {                                            \
      const char* rb_ = (BASE) + 32768 + (wn * 64 + n_ * 16 + lo) * 128;        \
      _Pragma("unroll")                                                         \
      for (int k_ = 0; k_ < 2; ++k_)                                            \
        bfr[n_][k_] = *(const bf16x8*)(rb_ + (((k_ * 4 + hi) ^ x7) << 4));      \
    }                                                                           \
  } while (0)

#define MFMA_Q(q)                                                               \
  do {                                                                          \
    __builtin_amdgcn_s_setprio(1);                                              \
    _Pragma("unroll")                                                           \
    for (int m_ = 0; m_ < 2; ++m_)                                              \
      _Pragma("unroll")                                                         \
      for (int n_ = 0; n_ < 4; ++n_)                                            \
        _Pragma("unroll")                                                       \
        for (int k_ = 0; k_ < 2; ++k_)                                          \
          acc[(q)*2 + m_][n_] = __builtin_amdgcn_mfma_f32_16x16x32_bf16(        \
              af[m_][k_], bfr[n_][k_], acc[(q)*2 + m_][n_], 0, 0, 0);           \
    __builtin_amdgcn_s_setprio(0);                                              \
  } while (0)

  // prologue: tile0 full (buf0) + tile1 B (buf1); wait tile0, t1.B in flight
  SA_HALF(0, 0, 0); SA_HALF(0, 0, 1);
  SB_HALF(0, 0, 0); SB_HALF(0, 0, 1);
  SB_HALF(1, 1, 0); SB_HALF(1, 1, 1);
  WAIT_VM(4);
  BAR;

  const char* E = lds;           // buf0: even tile
  const char* O = lds + 65536;   // buf1: odd tile

#pragma unroll 1
  for (int it = 0; it < 8; ++it) {
    const int last = (it == 7);
    // ---- p1: even tile q0; B-frags; stage odd.A0 (tile 2it+1) ----
    LDB(E); LDA(E, 0);
    SA_HALF(2 * it + 1, 1, 0);
    BAR; WAIT_LGKM0; MFMA_Q(0); BAR;
    // ---- p2: even q1; stage odd.A1 ----
    LDA(E, 1);
    SA_HALF(2 * it + 1, 1, 1);
    BAR; WAIT_LGKM0; MFMA_Q(1); BAR;
    // ---- p3: even q2; stage even.B0 (tile 2it+2) ----
    LDA(E, 2);
    if (!last) SB_HALF(2 * it + 2, 0, 0);
    BAR; WAIT_LGKM0; MFMA_Q(2); BAR;
    // ---- p4: even q3; stage even.B1; counted vmcnt (odd tile landed) ----
    LDA(E, 3);
    if (!last) { SB_HALF(2 * it + 2, 0, 1); WAIT_VM(4); }
    else       { WAIT_VM(0); }
    BAR; WAIT_LGKM0; MFMA_Q(3); BAR;
    // ---- p5: odd tile q0; B-frags; stage even.A0 (tile 2it+2) ----
    LDB(O); LDA(O, 0);
    if (!last) SA_HALF(2 * it + 2, 0, 0);
    BAR; WAIT_LGKM0; MFMA_Q(0); BAR;
    // ---- p6: odd q1; stage even.A1 ----
    LDA(O, 1);
    if (!last) SA_HALF(2 * it + 2, 0, 1);
    BAR; WAIT_LGKM0; MFMA_Q(1); BAR;
    // ---- p7: odd q2; stage odd.B0 (tile 2it+3) ----
    LDA(O, 2);
    if (!last) SB_HALF(2 * it + 3, 1, 0);
    BAR; WAIT_LGKM0; MFMA_Q(2); BAR;
    // ---- p8: odd q3; stage odd.B1; counted vmcnt (even tile landed) ----
    LDA(O, 3);
    if (!last) { SB_HALF(2 * it + 3, 1, 1); WAIT_VM(4); }
    BAR; WAIT_LGKM0; MFMA_Q(3); BAR;
  }

#undef MFMA_Q
#undef LDB
#undef LDA
#undef SB_HALF
#undef SA_HALF
#undef STAGE_HALF

  // epilogue: C/D layout col=lane&15, row=(lane>>4)*4+j
  float hrb[4];
#pragma unroll
  for (int n = 0; n < 4; ++n)
    hrb[n] = 0.5f * RB[bcol + wn * 64 + n * 16 + lo];
#pragma unroll
  for (int m = 0; m < 8; ++m) {
    const int rbase = wm * 128 + m * 16 + hi * 4;
#pragma unroll
    for (int j = 0; j < 4; ++j) {
      const int row = rbase + j;
      const float ha = 0.5f * RA[brow + row];
      float* orow = C + (size_t)(brow + row) * NM + bcol;
#pragma unroll
      for (int n = 0; n < 4; ++n)
        orow[wn * 64 + n * 16 + lo] = ha + hrb[n] - acc[m][n][j];
    }
  }
}

// ---------------- fallback: fused kernel (if ws too small) -----------------
static __device__ __forceinline__ int swz(int row, int colbytes) {
  return (row * 128 + colbytes) ^ ((row & 7) << 4);
}

__global__ __launch_bounds__(256, 2)
void hellinger_fused(const float* __restrict__ A, const float* __restrict__ B,
                     float* __restrict__ C) {
  __shared__ unsigned short As[128 * 64];
  __shared__ unsigned short Bs[128 * 64];
  __shared__ float sA[128];
  __shared__ float sB[128];

  const int t = threadIdx.x;
  const int lane = t & 63;
  const int wave = t >> 6;
  const int wrow = (wave >> 1) * 64;
  const int wcol = (wave & 1) * 64;
  const int brow = blockIdx.y * 128;
  const int bcol = blockIdx.x * 128;
  const int sr = t >> 4;
  const int sc = (t & 15) * 4;

  const float* ap = A + (size_t)(brow + sr) * DD + sc;
  const float* bp = B + (size_t)(bcol + sr) * DD + sc;

  float racc[8], cacc[8];
#pragma unroll
  for (int i = 0; i < 8; ++i) { racc[i] = 0.f; cacc[i] = 0.f; }

  f32x4 acc[4][4];
#pragma unroll
  for (int m = 0; m < 4; ++m)
#pragma unroll
    for (int n = 0; n < 4; ++n) acc[m][n] = (f32x4){0.f, 0.f, 0.f, 0.f};

  for (int kt = 0; kt < DD / 64; ++kt) {
#pragma unroll
    for (int i = 0; i < 8; ++i) {
      const float4 v = *(const float4*)(ap + (size_t)(i * 16) * DD + kt * 64);
      racc[i] += (v.x + v.y) + (v.z + v.w);
      ushort4 p;
      p.x = f2bf(sqrtf(v.x)); p.y = f2bf(sqrtf(v.y));
      p.z = f2bf(sqrtf(v.z)); p.w = f2bf(sqrtf(v.w));
      *(ushort4*)((char*)As + swz(i * 16 + sr, sc * 2)) = p;
    }
#pragma unroll
    for (int i = 0; i < 8; ++i) {
      const float4 v = *(const float4*)(bp + (size_t)(i * 16) * DD + kt * 64);
      cacc[i] += (v.x + v.y) + (v.z + v.w);
      ushort4 p;
      p.x = f2bf(sqrtf(v.x)); p.y = f2bf(sqrtf(v.y));
      p.z = f2bf(sqrtf(v.z)); p.w = f2bf(sqrtf(v.w));
      *(ushort4*)((char*)Bs + swz(i * 16 + sr, sc * 2)) = p;
    }
    __syncthreads();
#pragma unroll
    for (int kk = 0; kk < 2; ++kk) {
      const int koffb = kk * 64 + (lane >> 4) * 16;
      bf16x8 af[4], bfr[4];
#pragma unroll
      for (int m = 0; m < 4; ++m)
        af[m] = *(const bf16x8*)((const char*)As + swz(wrow + m * 16 + (lane & 15), koffb));
#pragma unroll
      for (int n = 0; n < 4; ++n)
        bfr[n] = *(const bf16x8*)((const char*)Bs + swz(wcol + n * 16 + (lane & 15), koffb));
#pragma unroll
      for (int m = 0; m < 4; ++m)
#pragma unroll
        for (int n = 0; n < 4; ++n)
          acc[m][n] = __builtin_amdgcn_mfma_f32_16x16x32_bf16(af[m], bfr[n], acc[m][n], 0, 0, 0);
    }
    __syncthreads();
  }

#pragma unroll
  for (int i = 0; i < 8; ++i) {
#pragma unroll
    for (int mask = 1; mask < 16; mask <<= 1) {
      racc[i] += __shfl_xor(racc[i], mask, 64);
      cacc[i] += __shfl_xor(cacc[i], mask, 64);
    }
  }
  if ((t & 15) == 0) {
#pragma unroll
    for (int i = 0; i < 8; ++i) { sA[i * 16 + sr] = racc[i]; sB[i * 16 + sr] = cacc[i]; }
  }
  __syncthreads();

#pragma unroll
  for (int m = 0; m < 4; ++m) {
    const int rbase = wrow + m * 16 + (lane >> 4) * 4;
#pragma unroll
    for (int j = 0; j < 4; ++j) {
      const int row = rbase + j;
      const float ha = 0.5f * sA[row];
      float* orow = C + (size_t)(brow + row) * NM + bcol;
#pragma unroll
      for (int n = 0; n < 4; ++n) {
        const int col = wcol + n * 16 + (lane & 15);
        orow[col] = ha + 0.5f * sB[col] - acc[m][n][j];
      }
    }
  }
}

extern "C" void kernel_launch(void* const* d_in, const int* in_sizes, int n_in,
                              void* d_out, int out_size, void* d_ws, size_t ws_size,
                              hipStream_t stream) {
  const float* a = (const float*)d_in[0];
  const float* b = (const float*)d_in[1];
  float* out = (float*)d_out;

  const size_t mat_bytes = (size_t)NM * DD * sizeof(unsigned short); // 16 MB
  const size_t need = 2 * mat_bytes + 2 * (size_t)NM * sizeof(float);

  if (ws_size >= need) {
    unsigned short* SA = (unsigned short*)d_ws;
    unsigned short* SB = (unsigned short*)((char*)d_ws + mat_bytes);
    float* RA = (float*)((char*)d_ws + 2 * mat_bytes);
    float* RB = RA + NM;
    hipLaunchKernelGGL(hell_prep, dim3(2 * NM), dim3(256), 0, stream,
                       a, b, SA, SB, RA, RB);
    hipLaunchKernelGGL(hell_gemm6, dim3(32 * 32), dim3(512), 0, stream,
                       SA, SB, RA, RB, out);
  } else {
    dim3 grid(NM / 128, NM / 128);
    hipLaunchKernelGGL(hellinger_fused, grid, dim3(256), 0, stream, a, b, out);
  }
}